// Round 10
// baseline (32.866 us; speedup 1.0000x reference)
//
#include <hip/hip_runtime.h>
#include <math.h>

// CropPoolLayer: TF crop_and_resize (bilinear, extrapolation=0) to 14x14
// fused with 2x2 max pool -> [N,7,7,C], NHWC fp32.
// bottom [B=2,H=64,W=64,C=512] fp32, rois [N,5] (bid,x1,y1,x2,y2), im_info[2].
//
// R10 = R9 (64-thr wave, F8 = 2 float4/thread, scalarized uniform-branch
// corner dedup, rcp normalize, nt stores, XCD swizzle) + CELL PAIRING:
// one wave processes two consecutive cells (usually horizontally adjacent,
// same ROI). Adjacent cells share corner columns; processing them on the
// same CU turns the overlap into L1 hits (~20% less L2 read traffic) and
// halves per-wave fixed overhead. A's X regs die before B's fresh chain,
// so peak VGPR stays ~X(64)+corners(32)+geom.

constexpr int POOLSZ = 7;
constexpr int CROPSZ = 14;
constexpr int Hc = 64, Wc = 64, C4 = 128;     // C=512 -> 128 float4 lanes

typedef float vfloat4 __attribute__((ext_vector_type(4)));

struct F8 { float4 lo, hi; };                  // 2 float4 per thread

__device__ __forceinline__ float4 lerp4(float4 a, float4 b, float t) {
    return make_float4(fmaf(b.x - a.x, t, a.x),
                       fmaf(b.y - a.y, t, a.y),
                       fmaf(b.z - a.z, t, a.z),
                       fmaf(b.w - a.w, t, a.w));
}
__device__ __forceinline__ F8 lerp8(const F8& a, const F8& b, float t) {
    F8 r; r.lo = lerp4(a.lo, b.lo, t); r.hi = lerp4(a.hi, b.hi, t); return r;
}
__device__ __forceinline__ float4 f4max(float4 a, float4 b) {
    return make_float4(fmaxf(a.x, b.x), fmaxf(a.y, b.y),
                       fmaxf(a.z, b.z), fmaxf(a.w, b.w));
}
__device__ __forceinline__ F8 f8max(const F8& a, const F8& b) {
    F8 r; r.lo = f4max(a.lo, b.lo); r.hi = f4max(a.hi, b.hi); return r;
}
__device__ __forceinline__ F8 mask8(const F8& v, bool ok) {
    F8 r;
    r.lo = ok ? v.lo : make_float4(0.f, 0.f, 0.f, 0.f);
    r.hi = ok ? v.hi : make_float4(0.f, 0.f, 0.f, 0.f);
    return r;
}
__device__ __forceinline__ int rfl(int x) { return __builtin_amdgcn_readfirstlane(x); }

struct Geom {
    int R0, R1, R2, R3;        // premultiplied row bases (float4 units)
    int cA, cB, cC, cD;        // premultiplied corner cols (float4 units)
    float lx0, lx1, ly0, ly1;  // unclipped lerp weights (per reference)
    bool v00, v01, v10, v11;   // sample validity
};

__device__ __forceinline__ void computeGeom(const float* __restrict__ rois,
                                            float inv_w, float inv_h,
                                            int blk, Geom& g)
{
    const int n  = blk / (POOLSZ * POOLSZ);
    const int p  = blk - n * (POOLSZ * POOLSZ);
    const int py = p / POOLSZ;
    const int px = p - py * POOLSZ;

    const float* r5 = rois + n * 5;
    const int bb = rfl((int)r5[0]);
    const float rx1 = r5[1] * inv_w, ry1 = r5[2] * inv_h;
    const float rx2 = r5[3] * inv_w, ry2 = r5[4] * inv_h;

    // TF grid: coord = p1*(D-1) + i * ((p2-p1)*(D-1)/(CROP-1))
    const float sy = (ry2 - ry1) * (float)(Hc - 1) / (float)(CROPSZ - 1);
    const float sx = (rx2 - rx1) * (float)(Wc - 1) / (float)(CROPSZ - 1);
    const float oy = ry1 * (float)(Hc - 1);
    const float ox = rx1 * (float)(Wc - 1);

    const float ysa = fmaf((float)(2 * py), sy, oy);
    const bool vy0 = (ysa >= 0.f) && (ysa <= (float)(Hc - 1));
    const float fy = floorf(ysa); g.ly0 = ysa - fy;            // unclipped
    const int y0 = (int)fminf(fmaxf(fy, 0.f), (float)(Hc - 1));
    const int y1 = (int)fminf(fmaxf(ceilf(ysa), 0.f), (float)(Hc - 1));
    g.R0 = rfl(((bb * Hc + y0) * Wc) * C4);
    g.R1 = rfl(((bb * Hc + y1) * Wc) * C4);

    const float ysb = fmaf((float)(2 * py + 1), sy, oy);
    const bool vy1 = (ysb >= 0.f) && (ysb <= (float)(Hc - 1));
    const float fy2 = floorf(ysb); g.ly1 = ysb - fy2;
    const int y2 = (int)fminf(fmaxf(fy2, 0.f), (float)(Hc - 1));
    const int y3 = (int)fminf(fmaxf(ceilf(ysb), 0.f), (float)(Hc - 1));
    g.R2 = rfl(((bb * Hc + y2) * Wc) * C4);
    g.R3 = rfl(((bb * Hc + y3) * Wc) * C4);

    const float xsa = fmaf((float)(2 * px), sx, ox);
    const bool vx0 = (xsa >= 0.f) && (xsa <= (float)(Wc - 1));
    const float fx = floorf(xsa); g.lx0 = xsa - fx;            // unclipped
    g.cA = rfl((int)fminf(fmaxf(fx, 0.f), (float)(Wc - 1)) * C4);
    g.cB = rfl((int)fminf(fmaxf(ceilf(xsa), 0.f), (float)(Wc - 1)) * C4);

    const float xsb = fmaf((float)(2 * px + 1), sx, ox);
    const bool vx1 = (xsb >= 0.f) && (xsb <= (float)(Wc - 1));
    const float fx2 = floorf(xsb); g.lx1 = xsb - fx2;
    g.cC = rfl((int)fminf(fmaxf(fx2, 0.f), (float)(Wc - 1)) * C4);
    g.cD = rfl((int)fminf(fmaxf(ceilf(xsb), 0.f), (float)(Wc - 1)) * C4);

    g.v00 = vy0 && vx0; g.v01 = vy0 && vx1;
    g.v10 = vy1 && vx0; g.v11 = vy1 && vx1;
}

__global__ __launch_bounds__(64)
void crop_pool_kernel(const float4* __restrict__ bot4,
                      const float* __restrict__ rois,
                      const float* __restrict__ im_info,
                      float4* __restrict__ out4, int npair)
{
    // bijective XCD swizzle over pairs (npair divisible by 8)
    const int bid  = blockIdx.x;
    const int pair = (bid & 7) * (npair >> 3) + (bid >> 3);
    const int blkA = pair * 2;
    const int blkB = blkA + 1;

    const float inv_w = 1.0f / im_info[1];     // im=1024 (pow2) -> exact
    const float inv_h = 1.0f / im_info[0];

    Geom gA, gB;
    computeGeom(rois, inv_w, inv_h, blkA, gA); // independent chains; compiler
    computeGeom(rois, inv_w, inv_h, blkB, gB); // interleaves the scalar work

    const int tid = threadIdx.x;               // two float4s: tid, tid+64

    // Process one cell: fresh chain (loads + x-lerp, uniform-branch dedup),
    // y-lerp, mask, max-pool, nt-store. A's X regs die before B starts.
    auto processCell = [&](const Geom& g, int blk) {
        F8 X00, X01, X10, X11, X20, X21, X30, X31;
        auto fresh = [&](int rb, F8& Xs0, F8& Xs1) {
            F8 a, b, c, d;
            a.lo = bot4[rb + g.cA + tid]; a.hi = bot4[rb + g.cA + tid + 64];
            if (g.cB != g.cA) { b.lo = bot4[rb + g.cB + tid]; b.hi = bot4[rb + g.cB + tid + 64]; }
            else b = a;
            if (g.cC == g.cA) c = a; else if (g.cC == g.cB) c = b;
            else { c.lo = bot4[rb + g.cC + tid]; c.hi = bot4[rb + g.cC + tid + 64]; }
            if (g.cD == g.cC) d = c; else if (g.cD == g.cB) d = b;
            else { d.lo = bot4[rb + g.cD + tid]; d.hi = bot4[rb + g.cD + tid + 64]; }
            Xs0 = lerp8(a, b, g.lx0);
            Xs1 = lerp8(c, d, g.lx1);
        };

        fresh(g.R0, X00, X01);
        if (g.R1 == g.R0)      { X10 = X00; X11 = X01; }
        else                     fresh(g.R1, X10, X11);
        if (g.R2 == g.R0)      { X20 = X00; X21 = X01; }
        else if (g.R2 == g.R1) { X20 = X10; X21 = X11; }
        else                     fresh(g.R2, X20, X21);
        if (g.R3 == g.R2)      { X30 = X20; X31 = X21; }
        else if (g.R3 == g.R1) { X30 = X10; X31 = X11; }
        else                     fresh(g.R3, X30, X31);

        // y-lerp (reference order: top + (bot-top)*ly), mask invalid to 0
        const F8 v00 = lerp8(X00, X10, g.ly0);
        const F8 v01 = lerp8(X01, X11, g.ly0);
        const F8 v10 = lerp8(X20, X30, g.ly1);
        const F8 v11 = lerp8(X21, X31, g.ly1);

        const F8 acc = f8max(
            f8max(mask8(v00, g.v00), mask8(v01, g.v01)),
            f8max(mask8(v10, g.v10), mask8(v11, g.v11)));

        const size_t ob = (size_t)blk * C4 + tid;
        vfloat4 s0; s0.x = acc.lo.x; s0.y = acc.lo.y; s0.z = acc.lo.z; s0.w = acc.lo.w;
        vfloat4 s1; s1.x = acc.hi.x; s1.y = acc.hi.y; s1.z = acc.hi.z; s1.w = acc.hi.w;
        __builtin_nontemporal_store(s0, reinterpret_cast<vfloat4*>(&out4[ob]));
        __builtin_nontemporal_store(s1, reinterpret_cast<vfloat4*>(&out4[ob + 64]));
    };

    processCell(gA, blkA);
    processCell(gB, blkB);     // overlapping corner cols -> L1 hits
}

extern "C" void kernel_launch(void* const* d_in, const int* in_sizes, int n_in,
                              void* d_out, int out_size, void* d_ws, size_t ws_size,
                              hipStream_t stream) {
    const float4* bottom  = (const float4*)d_in[0];
    const float*  rois    = (const float*)d_in[1];
    const float*  im_info = (const float*)d_in[2];
    float4* out = (float4*)d_out;

    const int N = in_sizes[1] / 5;               // 512 ROIs
    const int ncell = N * POOLSZ * POOLSZ;       // 25088
    const int npair = ncell / 2;                 // 12544 = 8 * 1568

    crop_pool_kernel<<<npair, 64, 0, stream>>>(bottom, rois, im_info, out, npair);
}